// Round 10
// baseline (356.469 us; speedup 1.0000x reference)
//
#include <hip/hip_runtime.h>
#include <cstdint>
#include <cstddef>

constexpr int Bn = 64, Tn = 1024, Hn = 256, Kn = 4;
constexpr int MROWS = 32;           // output t-rows per block
constexpr int SROWS = MROWS + 2;    // staged input rows
constexpr int SST   = 36;           // LDS srow stride (144 B, 16B-aligned)
constexpr int CHI   = 4;            // i-values per B chunk
constexpr int NCH   = Hn / CHI;     // 64 chunks
constexpr int HHALF = 128;          // A channels staged per half

// Pack conv_w [o][i][dt] -> wP[(dt*256+i)][o]
__global__ __launch_bounds__(256) void pack_w_k(const float* __restrict__ conv_w,
                                                float* __restrict__ wP) {
  int o  = threadIdx.x;
  int kk = blockIdx.x;              // kk = dt*256 + i
  int dt = kk >> 8, i = kk & 255;
  wP[kk * Hn + o] = conv_w[o * (Hn * 3) + i * 3 + dt];
}

// async global->LDS, 16B per lane (dest = wave-uniform base + lane*16)
__device__ __forceinline__ void gload_lds16(const float* g, float* l) {
  __builtin_amdgcn_global_load_lds(
      (const __attribute__((address_space(1))) void*)g,
      (__attribute__((address_space(3))) void*)l, 16, 0, 0);
}

// One chunk of compute. CURB = byte offset of B buffer (0 or 12288),
// AOFF = byte offset of this chunk's A base within the pair (0 or 576).
// All LDS reads: hoisted vaddr + compile-time immediate offset.
#define COMPUTE(CURB, AOFF)                                                   \
  {                                                                           \
    _Pragma("unroll")                                                         \
    for (int ii = 0; ii < CHI; ++ii) {                                        \
      const char* ap = pa + (AOFF) + ii * (SST * 4);                          \
      const float4 a01 = *reinterpret_cast<const float4*>(ap);                \
      const float4 a23 = *reinterpret_cast<const float4*>(ap + 16);           \
      const float2 a45 = *reinterpret_cast<const float2*>(ap + 32);           \
      const float a[10] = {a01.x, a01.y, a01.z, a01.w,                        \
                           a23.x, a23.y, a23.z, a23.w, a45.x, a45.y};         \
      _Pragma("unroll")                                                       \
      for (int dt = 0; dt < 3; ++dt) {                                        \
        const float4 bq = *reinterpret_cast<const float4*>(                   \
            vBb + (CURB) + (dt * CHI + ii) * 1024);                           \
        const float bb[4] = {bq.x, bq.y, bq.z, bq.w};                         \
        _Pragma("unroll")                                                     \
        for (int rr = 0; rr < 8; ++rr)                                        \
          _Pragma("unroll")                                                   \
          for (int j = 0; j < 4; ++j)                                         \
            acc[rr][j] = fmaf(a[rr + dt], bb[j], acc[rr][j]);                 \
      }                                                                       \
    }                                                                         \
  }

// Fused conv1d(k=3,pad=1)+bias+ReLU+Linear(256->4): em[B,T,4] fp32.
// Round-9 structure (8 t-rows x 4 n-cols/thread, CHI=4, A in two halves,
// B via global_load_lds, 43,008 B LDS -> 3 blocks/CU) with the chunk loop
// unrolled x2 so ALL per-chunk LDS addresses are imm offsets; stage
// pointers hoisted (3 global + 6 LDS dests).
__global__ __launch_bounds__(256, 2) void emis_k(const float* __restrict__ x,
    const float* __restrict__ wP, const float* __restrict__ conv_b,
    const float* __restrict__ lin_w, const float* __restrict__ lin_b,
    float* __restrict__ em) {
  __shared__ float xsT[HHALF * SST];         // [chanLocal][srow], 18,432 B
  __shared__ float bufB[2 * 3 * CHI * Hn];   // flat, 24,576 B

  const int b  = blockIdx.y, t0 = blockIdx.x * MROWS;
  const int tid = threadIdx.x;
  const int ng4 = tid & 63;         // cols ng4*4 .. +3
  const int mg  = tid >> 6;         // rows 8*mg .. +7 (one mg per wave)
  const int lane = tid & 63;

  const float4* x4 = reinterpret_cast<const float4*>(x + (size_t)b * Tn * Hn);

  // ---- hoisted B-stage pointers: wave mg stages rows (dt, ii=mg),
  // dt=0,1,2 -> LDS rows r = dt*4+mg. Global bump = +4 wP rows/chunk. ----
  const float* gB0 = wP + (size_t)(0 * 256 + mg) * Hn + lane * 4;
  const float* gB1 = wP + (size_t)(1 * 256 + mg) * Hn + lane * 4;
  const float* gB2 = wP + (size_t)(2 * 256 + mg) * Hn + lane * 4;
  float* d00 = bufB + 0 * 3072 + (0 * 4 + mg) * Hn + lane * 4;
  float* d01 = bufB + 0 * 3072 + (1 * 4 + mg) * Hn + lane * 4;
  float* d02 = bufB + 0 * 3072 + (2 * 4 + mg) * Hn + lane * 4;
  float* d10 = bufB + 1 * 3072 + (0 * 4 + mg) * Hn + lane * 4;
  float* d11 = bufB + 1 * 3072 + (1 * 4 + mg) * Hn + lane * 4;
  float* d12 = bufB + 1 * 3072 + (2 * 4 + mg) * Hn + lane * 4;

  // ---- A staging: chans [k0, k0+128) transposed into xsT[local][srow] ----
  auto stageA = [&](int k0) {
    for (int idx = tid; idx < SROWS * (HHALF / 4); idx += 256) {  // 1088
      int row = idx >> 5, c4 = idx & 31;
      int t = t0 - 1 + row;
      float4 v = make_float4(0.f, 0.f, 0.f, 0.f);
      if (t >= 0 && t < Tn) v = x4[t * (Hn / 4) + (k0 >> 2) + c4];
      int i = c4 << 2;
      xsT[(i + 0) * SST + row] = v.x;
      xsT[(i + 1) * SST + row] = v.y;
      xsT[(i + 2) * SST + row] = v.z;
      xsT[(i + 3) * SST + row] = v.w;
    }
  };

  // ---- prologue: B chunk 0 (async) + A half 0, one barrier ----
  gload_lds16(gB0, d00); gload_lds16(gB1, d01); gload_lds16(gB2, d02);
  gB0 += 4 * Hn; gB1 += 4 * Hn; gB2 += 4 * Hn;
  stageA(0);
  __syncthreads();

  float acc[8][4];
  #pragma unroll
  for (int rr = 0; rr < 8; ++rr)
    #pragma unroll
    for (int j = 0; j < 4; ++j) acc[rr][j] = 0.f;

  const char* const pa0 = reinterpret_cast<const char*>(xsT) + 8 * mg * 4;
  const char* pa = pa0;
  const char* const vBb = reinterpret_cast<const char*>(bufB) + ng4 * 16;

  #pragma unroll 1
  for (int half = 0; half < 2; ++half) {
    if (half) {                      // switch to A half 1 (chans 128..255)
      stageA(HHALF);                 // safe: previous chunk's end barrier
      __syncthreads();
      pa = pa0;
    }
    #pragma unroll 1
    for (int cp = 0; cp < 16; ++cp) {
      // ---- even chunk (cur=0): stage next into buf1 ----
      gload_lds16(gB0, d10); gload_lds16(gB1, d11); gload_lds16(gB2, d12);
      gB0 += 4 * Hn; gB1 += 4 * Hn; gB2 += 4 * Hn;
      COMPUTE(0, 0);
      __syncthreads();
      // ---- odd chunk (cur=1): stage next into buf0 (unless last) ----
      if (!(half == 1 && cp == 15)) {
        gload_lds16(gB0, d00); gload_lds16(gB1, d01); gload_lds16(gB2, d02);
        gB0 += 4 * Hn; gB1 += 4 * Hn; gB2 += 4 * Hn;
      }
      COMPUTE(12288, 576);
      __syncthreads();
      pa += 1152;
    }
  }

  // ---- Epilogue: +conv_b, ReLU, x lin_w^T over this thread's 4 cols ----
  float pem[8][4];
  #pragma unroll
  for (int rr = 0; rr < 8; ++rr)
    #pragma unroll
    for (int k = 0; k < 4; ++k) pem[rr][k] = 0.f;

  const int n0 = ng4 * 4;
  #pragma unroll
  for (int j = 0; j < 4; ++j) {
    const int n = n0 + j;
    const float cb = conv_b[n];
    const float l0 = lin_w[0 * Hn + n];
    const float l1 = lin_w[1 * Hn + n];
    const float l2 = lin_w[2 * Hn + n];
    const float l3 = lin_w[3 * Hn + n];
    #pragma unroll
    for (int rr = 0; rr < 8; ++rr) {
      float v = fmaxf(acc[rr][j] + cb, 0.f);
      pem[rr][0] = fmaf(v, l0, pem[rr][0]);
      pem[rr][1] = fmaf(v, l1, pem[rr][1]);
      pem[rr][2] = fmaf(v, l2, pem[rr][2]);
      pem[rr][3] = fmaf(v, l3, pem[rr][3]);
    }
  }
  #pragma unroll
  for (int rr = 0; rr < 8; ++rr)
    #pragma unroll
    for (int k = 0; k < 4; ++k) {
      float v = pem[rr][k];
      v += __shfl_xor(v, 1);
      v += __shfl_xor(v, 2);
      v += __shfl_xor(v, 4);
      v += __shfl_xor(v, 8);
      v += __shfl_xor(v, 16);
      v += __shfl_xor(v, 32);
      pem[rr][k] = v;
    }
  if (ng4 == 0) {
    #pragma unroll
    for (int rr = 0; rr < 8; ++rr) {
      const int m = 8 * mg + rr;
      float4 o;
      o.x = pem[rr][0] + lin_b[0];
      o.y = pem[rr][1] + lin_b[1];
      o.z = pem[rr][2] + lin_b[2];
      o.w = pem[rr][3] + lin_b[3];
      *reinterpret_cast<float4*>(em + (size_t)(b * Tn + t0 + m) * 4) = o;
    }
  }
}

// byte-map composition c(k) = a(b(k))
__device__ __forceinline__ unsigned int compose_map(unsigned int a, unsigned int b) {
#if __has_builtin(__builtin_amdgcn_perm)
  return __builtin_amdgcn_perm(a, a, b);
#else
  unsigned int c = 0;
  #pragma unroll
  for (int k = 0; k < 4; ++k) {
    unsigned int sel = (b >> (8 * k)) & 0xffu;
    c |= ((a >> (8 * sel)) & 0xffu) << (8 * k);
  }
  return c;
#endif
}

// quad_perm broadcast of lane J (within each 4-lane quad) via DPP
template <int J>
__device__ __forceinline__ float qb(float v) {
  return __int_as_float(__builtin_amdgcn_update_dpp(
      0, __float_as_int(v), (J * 0x55), 0xf, 0xf, true));
}

// One quad-parallel Viterbi step for lane k: c_j = bcast_j(s) + tr[j][k];
// s = max(c0..c3) + e. Values bitwise-identical to the scalar form.
#define PSTEP(EV, T)                                                       \
  {                                                                        \
    shf[((T) - 1) * 4 + kk] = s;                                           \
    float c0 = qb<0>(s) + trc0;                                            \
    float c1 = qb<1>(s) + trc1;                                            \
    float c2 = qb<2>(s) + trc2;                                            \
    float c3 = qb<3>(s) + trc3;                                            \
    s = fmaxf(fmaxf(c0, c1), fmaxf(c2, c3)) + (EV);                        \
  }

// CRF Viterbi decode. Forward: 4-lane quad-parallel scan (lane k owns
// state k), 8-deep per-lane emission prefetch. Backtrace: 64 lanes rebuild
// argmax maps (exact per-candidate (s+tr)+e form, first-wins), v_perm
// suffix-scan (integer-exact).
__global__ __launch_bounds__(64) void viterbi_k(const float* __restrict__ em,
    const float* __restrict__ cstart, const float* __restrict__ cend,
    const float* __restrict__ ctrans, int* __restrict__ out) {
  __shared__ float4 se[Tn];          // emissions, 16 KB
  __shared__ float4 sh[Tn - 1];      // score vector BEFORE step t+1, 16 KB
  __shared__ int s_last;
  const int b = blockIdx.x, lane = threadIdx.x;
  const float4* e4 = reinterpret_cast<const float4*>(em + (size_t)b * Tn * Kn);
  for (int i = lane; i < Tn; i += 64) se[i] = e4[i];
  float tr[4][4];
  #pragma unroll
  for (int j = 0; j < 4; ++j)
    #pragma unroll
    for (int k = 0; k < 4; ++k) tr[j][k] = ctrans[j * 4 + k];
  __syncthreads();

  if (lane < 4) {
    const int kk = lane;
    const float* sef = reinterpret_cast<const float*>(se);
    float* shf = reinterpret_cast<float*>(sh);
    const float trc0 = ctrans[0 * 4 + kk];
    const float trc1 = ctrans[1 * 4 + kk];
    const float trc2 = ctrans[2 * 4 + kk];
    const float trc3 = ctrans[3 * 4 + kk];
    float s = cstart[kk] + sef[kk];
    float e[8];
    #pragma unroll
    for (int d = 0; d < 8; ++d) e[d] = sef[(1 + d) * 4 + kk];
    int t = 1;
    #pragma unroll 1
    for (int g = 0; g < 127; ++g, t += 8) {   // t = 1..1016
      float f[8];
      #pragma unroll
      for (int d = 0; d < 8; ++d) f[d] = e[d];
      #pragma unroll
      for (int d = 0; d < 8; ++d) e[d] = sef[(t + 8 + d) * 4 + kk];  // last
      // group reads a few words into sh[] (defined LDS): harmless.
      PSTEP(f[0], t);     PSTEP(f[1], t + 1);
      PSTEP(f[2], t + 2); PSTEP(f[3], t + 3);
      PSTEP(f[4], t + 4); PSTEP(f[5], t + 5);
      PSTEP(f[6], t + 6); PSTEP(f[7], t + 7);
    }
    // tail: t = 1017..1023 (e[0..6] hold se[1017..1023])
    PSTEP(e[0], 1017); PSTEP(e[1], 1018); PSTEP(e[2], 1019);
    PSTEP(e[3], 1020); PSTEP(e[4], 1021); PSTEP(e[5], 1022);
    PSTEP(e[6], 1023);
    s += cend[kk];
    float f0 = __shfl(s, 0), f1 = __shfl(s, 1);
    float f2 = __shfl(s, 2), f3 = __shfl(s, 3);
    if (kk == 0) {
      int tag = 0; float bf = f0;
      if (f1 > bf) { bf = f1; tag = 1; }
      if (f2 > bf) { bf = f2; tag = 2; }
      if (f3 > bf) { bf = f3; tag = 3; }
      s_last = tag;
    }
  }
  __syncthreads();

  // ---- parallel backtrace: lane owns maps t in [16*lane, 16*lane+15] ----
  const unsigned int ID = 0x03020100u;
  unsigned int mloc[16];
  const int t0 = lane * 16;
  #pragma unroll
  for (int k = 0; k < 16; ++k) {
    const int t = t0 + k;
    if (t < Tn - 1) {
      const float4 s = sh[t];
      const float4 e = se[t + 1];
      const float sj[4] = {s.x, s.y, s.z, s.w};
      const float ev[4] = {e.x, e.y, e.z, e.w};
      unsigned int mw = 0;
      #pragma unroll
      for (int kk = 0; kk < 4; ++kk) {
        float best = (sj[0] + tr[0][kk]) + ev[kk];
        int bi = 0;
        #pragma unroll
        for (int j = 1; j < 4; ++j) {
          float cc = (sj[j] + tr[j][kk]) + ev[kk];
          if (cc > best) { best = cc; bi = j; }
        }
        mw |= (unsigned)bi << (8 * kk);
      }
      mloc[k] = mw;
    } else {
      mloc[k] = ID;
    }
  }
  unsigned int P = mloc[15];
  #pragma unroll
  for (int k = 14; k >= 0; --k) P = compose_map(mloc[k], P);
  #pragma unroll
  for (int d = 1; d < 64; d <<= 1) {
    unsigned int q = (unsigned int)__shfl_down((int)P, d);
    if (lane + d > 63) q = ID;
    P = compose_map(P, q);
  }
  unsigned int E = (unsigned int)__shfl_down((int)P, 1);  // exclusive suffix
  if (lane == 63) E = ID;
  const int last = s_last;
  unsigned int tag = (E >> (8 * last)) & 3u;
  int* ob = out + (size_t)b * Tn;
  #pragma unroll
  for (int k = 15; k >= 0; --k) {
    tag = (mloc[k] >> (8 * tag)) & 3u;
    ob[t0 + k] = (int)tag;
  }
}

extern "C" void kernel_launch(void* const* d_in, const int* in_sizes, int n_in,
                              void* d_out, int out_size, void* d_ws, size_t ws_size,
                              hipStream_t stream) {
  const float* x      = (const float*)d_in[0];
  const float* conv_w = (const float*)d_in[1];
  const float* conv_b = (const float*)d_in[2];
  const float* lin_w  = (const float*)d_in[3];
  const float* lin_b  = (const float*)d_in[4];
  const float* cstart = (const float*)d_in[5];
  const float* cend   = (const float*)d_in[6];
  const float* ctrans = (const float*)d_in[7];
  int* out = (int*)d_out;

  float* wP = (float*)d_ws;                      // 768*256 floats
  float* em = wP + 768 * 256;                    // 64*1024*4 floats

  pack_w_k<<<768, 256, 0, stream>>>(conv_w, wP);
  emis_k<<<dim3(Tn / MROWS, Bn), 256, 0, stream>>>(x, wP, conv_b, lin_w, lin_b, em);
  viterbi_k<<<Bn, 64, 0, stream>>>(em, cstart, cend, ctrans, out);
}

// Round 11
// 148.448 us; speedup vs baseline: 2.4013x; 2.4013x over previous
//
#include <hip/hip_runtime.h>
#include <cstdint>
#include <cstddef>

typedef __attribute__((ext_vector_type(8))) short short8;
typedef __attribute__((ext_vector_type(4))) float f32x4;

constexpr int Bn = 64, Tn = 1024, Hn = 256, Kn = 4;
constexpr int TT = 128;           // T-rows per block
constexpr int AROWS = TT + 2;     // 130 staged x-rows (t0-1 .. t0+128)
constexpr int ARSTR = 144;        // A-LDS row stride bytes (128 data + 16 pad)

// round-to-nearest-even fp32 -> bf16 bits
__device__ __forceinline__ unsigned bf16rne(float f) {
  unsigned u = __float_as_uint(f);
  return (u + 0x7fffu + ((u >> 16) & 1u)) >> 16;
}

// Pack conv_w into MFMA-B-fragment-ready hi/lo bf16:
// Bp[fid(24 ks x 2 p x 16 nf)][lane(64)][j(8)], value = part_p(conv_w[n][i][dt])
// where k = ks*32 + (lane>>4)*8 + j (dt=k>>8, i=k&255), n = nf*16 + (lane&15).
__global__ __launch_bounds__(256) void pack_b_k(const float* __restrict__ conv_w,
                                                unsigned short* __restrict__ Bp) {
  int gt = blockIdx.x * 256 + threadIdx.x;   // 0..49151
  int fid = gt >> 6, l = gt & 63;
  int ks = fid >> 5, rem = fid & 31;
  int p = rem >> 4, nf = rem & 15;
  int n = nf * 16 + (l & 15);
  int k0 = ks * 32 + ((l >> 4) << 3);
  short8 s;
  #pragma unroll
  for (int j = 0; j < 8; ++j) {
    int k = k0 + j;
    int dt = k >> 8, i = k & 255;
    float w = conv_w[n * 768 + i * 3 + dt];
    unsigned hb = bf16rne(w);
    if (p == 0) s[j] = (short)hb;
    else        s[j] = (short)bf16rne(w - __uint_as_float(hb << 16));
  }
  *reinterpret_cast<short8*>(Bp + (size_t)fid * 512 + l * 8) = s;
}

// async global->LDS, 16B/lane (dest = wave-uniform base + lane*16)
__device__ __forceinline__ void gload_lds16(const void* g, void* l) {
  __builtin_amdgcn_global_load_lds(
      (const __attribute__((address_space(1))) void*)g,
      (__attribute__((address_space(3))) void*)l, 16, 0, 0);
}

// Fused conv1d(k=3,pad=1)+bias+ReLU+Linear(256->4) via bf16 4-way-split MFMA.
// Block: 128(T) x 128(N), 4 waves (64x64 each = 4x4 16x16 frags).
// A: x rows t0-1..t0+128, hi/lo bf16 in LDS [row][p][32ch] (144B stride),
//    staged per 32-chan group (8 groups), each serving dt=0,1,2 slices.
// B: frag-packed hi/lo from Bp via global_load_lds, double-buffered.
// Output: PARTIAL emissions em2[b][t][ny][4] (N-half ny); viterbi combines.
__global__ __launch_bounds__(256, 3) void emis_k(const float* __restrict__ x,
    const unsigned short* __restrict__ Bp, const float* __restrict__ conv_b,
    const float* __restrict__ lin_w, float* __restrict__ em2) {
  __shared__ __align__(16) char A_lds[AROWS * ARSTR];   // 18,720 B
  __shared__ __align__(16) char B_lds[2 * 16 * 1024];   // 32,768 B

  const int b = blockIdx.z, ny = blockIdx.y, t0 = blockIdx.x * TT;
  const int tid = threadIdx.x, lane = tid & 63, w = tid >> 6;
  const int wm = w >> 1, wn = w & 1;
  const int nf0 = ny * 8;
  const float* xb = x + (size_t)b * Tn * Hn;

  auto stageA = [&](int ig) {
    #pragma unroll 1
    for (int it = 0; it < 5; ++it) {
      int idx = it * 256 + tid;
      if (idx < AROWS * 8) {
        int row = idx >> 3, c4 = idx & 7;
        int trow = t0 - 1 + row;
        float4 v = make_float4(0.f, 0.f, 0.f, 0.f);
        if (trow >= 0 && trow < Tn)
          v = *reinterpret_cast<const float4*>(xb + (size_t)trow * Hn + ig * 32 + c4 * 4);
        unsigned h[4], lo[4];
        float vf[4] = {v.x, v.y, v.z, v.w};
        #pragma unroll
        for (int q = 0; q < 4; ++q) {
          h[q] = bf16rne(vf[q]);
          lo[q] = bf16rne(vf[q] - __uint_as_float(h[q] << 16));
        }
        uint2 hp, lp;
        hp.x = h[0] | (h[1] << 16);  hp.y = h[2] | (h[3] << 16);
        lp.x = lo[0] | (lo[1] << 16); lp.y = lo[2] | (lo[3] << 16);
        char* base = A_lds + row * ARSTR + c4 * 8;
        *reinterpret_cast<uint2*>(base) = hp;        // hi plane (p=0)
        *reinterpret_cast<uint2*>(base + 64) = lp;   // lo plane (p=1)
      }
    }
  };

  auto stageB = [&](int sel, int ks) {
    #pragma unroll
    for (int q = 0; q < 4; ++q) {
      int fi = w * 4 + q;               // 0..15 = p*8 + nfl
      int p = fi >> 3, nfl = fi & 7;
      const char* src = reinterpret_cast<const char*>(Bp)
          + ((size_t)((ks * 2 + p) * 16 + nf0 + nfl)) * 1024 + lane * 16;
      char* dst = B_lds + sel * 16384 + fi * 1024 + lane * 16;
      gload_lds16(src, dst);
    }
  };

  f32x4 acc[4][4];
  #pragma unroll
  for (int mf = 0; mf < 4; ++mf)
    #pragma unroll
    for (int nf = 0; nf < 4; ++nf) acc[mf][nf] = (f32x4)0.f;

  // per-lane bases. A-frag: row=(lane&15), k-chans=(lane>>4)*8 (16B), +wm block
  const char* aB = A_lds + (lane & 15) * ARSTR + ((lane >> 4) << 4) + wm * 64 * ARSTR;
  const char* bB = B_lds + lane * 16 + wn * 4096;

  stageB(0, 0);
  stageA(0);
  __syncthreads();

  int sel = 0;
  #pragma unroll 1
  for (int ig = 0; ig < 8; ++ig) {
    #pragma unroll 1
    for (int dt = 0; dt < 3; ++dt) {
      const int ks = dt * 8 + ig;
      const int nks = (dt < 2) ? ks + 8 : (ig < 7 ? ig + 1 : -1);
      if (nks >= 0) stageB(sel ^ 1, nks);   // async, lands during compute

      short8 Bh[4], Bl[4];
      #pragma unroll
      for (int nf = 0; nf < 4; ++nf) {
        Bh[nf] = *reinterpret_cast<const short8*>(bB + sel * 16384 + nf * 1024);
        Bl[nf] = *reinterpret_cast<const short8*>(bB + sel * 16384 + 8192 + nf * 1024);
      }
      #pragma unroll
      for (int mf = 0; mf < 4; ++mf) {
        const char* ap = aB + (mf * 16 + dt) * ARSTR;
        short8 Ah = *reinterpret_cast<const short8*>(ap);
        short8 Al = *reinterpret_cast<const short8*>(ap + 64);
        #pragma unroll
        for (int nf = 0; nf < 4; ++nf) {
          f32x4 c = acc[mf][nf];
          c = __builtin_amdgcn_mfma_f32_16x16x32_bf16(Ah, Bh[nf], c, 0, 0, 0);
          c = __builtin_amdgcn_mfma_f32_16x16x32_bf16(Al, Bh[nf], c, 0, 0, 0);
          c = __builtin_amdgcn_mfma_f32_16x16x32_bf16(Ah, Bl[nf], c, 0, 0, 0);
          c = __builtin_amdgcn_mfma_f32_16x16x32_bf16(Al, Bl[nf], c, 0, 0, 0);
          acc[mf][nf] = c;
        }
      }
      if (dt == 2 && ig < 7) { __syncthreads(); stageA(ig + 1); }
      __syncthreads();
      sel ^= 1;
    }
  }

  // ---- Epilogue: +conv_b, ReLU, x lin_w^T partials over this wave's cols ----
  // C/D layout: col = lane&15, row = (lane>>4)*4 + v  (m89-verified).
  f32x4 pem[4][4];   // [mf][v] -> 4 kk partial sums
  #pragma unroll
  for (int mf = 0; mf < 4; ++mf)
    #pragma unroll
    for (int v = 0; v < 4; ++v) pem[mf][v] = (f32x4)0.f;

  #pragma unroll
  for (int nf = 0; nf < 4; ++nf) {
    const int gcol = ny * 128 + wn * 64 + nf * 16 + (lane & 15);
    const float cb = conv_b[gcol];
    f32x4 lw;
    lw[0] = lin_w[gcol]; lw[1] = lin_w[256 + gcol];
    lw[2] = lin_w[512 + gcol]; lw[3] = lin_w[768 + gcol];
    #pragma unroll
    for (int mf = 0; mf < 4; ++mf)
      #pragma unroll
      for (int v = 0; v < 4; ++v) {
        float val = fmaxf(acc[mf][nf][v] + cb, 0.f);
        pem[mf][v] += val * lw;
      }
  }
  // reduce over the 16 col-lanes (lane bits 0..3)
  #pragma unroll
  for (int mf = 0; mf < 4; ++mf)
    #pragma unroll
    for (int v = 0; v < 4; ++v) {
      f32x4 t = pem[mf][v];
      #pragma unroll
      for (int m = 1; m < 16; m <<= 1) {
        f32x4 q;
        q[0] = __shfl_xor(t[0], m); q[1] = __shfl_xor(t[1], m);
        q[2] = __shfl_xor(t[2], m); q[3] = __shfl_xor(t[3], m);
        t += q;
      }
      pem[mf][v] = t;
    }
  // cross-wave (wn) combine via LDS (reuse A_lds after final barrier)
  float* red = reinterpret_cast<float*>(A_lds);   // [128 rows][2 wn][4 kk]
  if ((lane & 15) == 0) {
    const int g = lane >> 4;
    #pragma unroll
    for (int mf = 0; mf < 4; ++mf)
      #pragma unroll
      for (int v = 0; v < 4; ++v) {
        int r = wm * 64 + mf * 16 + g * 4 + v;
        *reinterpret_cast<f32x4*>(red + (r * 2 + wn) * 4) = pem[mf][v];
      }
  }
  __syncthreads();
  if (tid < 128) {
    f32x4 s0 = *reinterpret_cast<f32x4*>(red + tid * 8);
    f32x4 s1 = *reinterpret_cast<f32x4*>(red + tid * 8 + 4);
    f32x4 s = s0 + s1;
    *reinterpret_cast<f32x4*>(em2 + ((size_t)(b * Tn + t0 + tid) * 2 + ny) * 4) = s;
  }
}

// byte-map composition c(k) = a(b(k))
__device__ __forceinline__ unsigned int compose_map(unsigned int a, unsigned int b) {
#if __has_builtin(__builtin_amdgcn_perm)
  return __builtin_amdgcn_perm(a, a, b);
#else
  unsigned int c = 0;
  #pragma unroll
  for (int k = 0; k < 4; ++k) {
    unsigned int sel = (b >> (8 * k)) & 0xffu;
    c |= ((a >> (8 * sel)) & 0xffu) << (8 * k);
  }
  return c;
#endif
}

// quad_perm broadcast of lane J (within each 4-lane quad) via DPP
template <int J>
__device__ __forceinline__ float qb(float v) {
  return __int_as_float(__builtin_amdgcn_update_dpp(
      0, __float_as_int(v), (J * 0x55), 0xf, 0xf, true));
}

// One quad-parallel Viterbi step for lane k (values bitwise = scalar form).
#define PSTEP(EV, T)                                                       \
  {                                                                        \
    shf[((T) - 1) * 4 + kk] = s;                                           \
    float c0 = qb<0>(s) + trc0;                                            \
    float c1 = qb<1>(s) + trc1;                                            \
    float c2 = qb<2>(s) + trc2;                                            \
    float c3 = qb<3>(s) + trc3;                                            \
    s = fmaxf(fmaxf(c0, c1), fmaxf(c2, c3)) + (EV);                        \
  }

// CRF Viterbi decode. Stage: se[t] = em2[t][half0] + em2[t][half1] + lin_b.
// Forward: 4-lane quad-parallel scan. Backtrace: 64 lanes rebuild argmax
// maps, v_perm suffix-scan (integer-exact).
__global__ __launch_bounds__(64) void viterbi_k(const float* __restrict__ em2,
    const float* __restrict__ lin_b, const float* __restrict__ cstart,
    const float* __restrict__ cend, const float* __restrict__ ctrans,
    int* __restrict__ out) {
  __shared__ float4 se[Tn];          // emissions, 16 KB
  __shared__ float4 sh[Tn - 1];      // score vector BEFORE step t+1, 16 KB
  __shared__ int s_last;
  const int b = blockIdx.x, lane = threadIdx.x;
  const float4* e2 = reinterpret_cast<const float4*>(em2 + (size_t)b * Tn * 8);
  const float lb0 = lin_b[0], lb1 = lin_b[1], lb2 = lin_b[2], lb3 = lin_b[3];
  for (int i = lane; i < Tn; i += 64) {
    float4 a = e2[i * 2], c = e2[i * 2 + 1];
    se[i] = make_float4(a.x + c.x + lb0, a.y + c.y + lb1,
                        a.z + c.z + lb2, a.w + c.w + lb3);
  }
  float tr[4][4];
  #pragma unroll
  for (int j = 0; j < 4; ++j)
    #pragma unroll
    for (int k = 0; k < 4; ++k) tr[j][k] = ctrans[j * 4 + k];
  __syncthreads();

  if (lane < 4) {
    const int kk = lane;
    const float* sef = reinterpret_cast<const float*>(se);
    float* shf = reinterpret_cast<float*>(sh);
    const float trc0 = ctrans[0 * 4 + kk];
    const float trc1 = ctrans[1 * 4 + kk];
    const float trc2 = ctrans[2 * 4 + kk];
    const float trc3 = ctrans[3 * 4 + kk];
    float s = cstart[kk] + sef[kk];
    float e[8];
    #pragma unroll
    for (int d = 0; d < 8; ++d) e[d] = sef[(1 + d) * 4 + kk];
    int t = 1;
    #pragma unroll 1
    for (int g = 0; g < 127; ++g, t += 8) {   // t = 1..1016
      float f[8];
      #pragma unroll
      for (int d = 0; d < 8; ++d) f[d] = e[d];
      #pragma unroll
      for (int d = 0; d < 8; ++d) e[d] = sef[(t + 8 + d) * 4 + kk];
      PSTEP(f[0], t);     PSTEP(f[1], t + 1);
      PSTEP(f[2], t + 2); PSTEP(f[3], t + 3);
      PSTEP(f[4], t + 4); PSTEP(f[5], t + 5);
      PSTEP(f[6], t + 6); PSTEP(f[7], t + 7);
    }
    PSTEP(e[0], 1017); PSTEP(e[1], 1018); PSTEP(e[2], 1019);
    PSTEP(e[3], 1020); PSTEP(e[4], 1021); PSTEP(e[5], 1022);
    PSTEP(e[6], 1023);
    s += cend[kk];
    float f0 = __shfl(s, 0), f1 = __shfl(s, 1);
    float f2 = __shfl(s, 2), f3 = __shfl(s, 3);
    if (kk == 0) {
      int tag = 0; float bf = f0;
      if (f1 > bf) { bf = f1; tag = 1; }
      if (f2 > bf) { bf = f2; tag = 2; }
      if (f3 > bf) { bf = f3; tag = 3; }
      s_last = tag;
    }
  }
  __syncthreads();

  const unsigned int ID = 0x03020100u;
  unsigned int mloc[16];
  const int t0 = lane * 16;
  #pragma unroll
  for (int k = 0; k < 16; ++k) {
    const int t = t0 + k;
    if (t < Tn - 1) {
      const float4 s = sh[t];
      const float4 e = se[t + 1];
      const float sj[4] = {s.x, s.y, s.z, s.w};
      const float ev[4] = {e.x, e.y, e.z, e.w};
      unsigned int mw = 0;
      #pragma unroll
      for (int kk = 0; kk < 4; ++kk) {
        float best = (sj[0] + tr[0][kk]) + ev[kk];
        int bi = 0;
        #pragma unroll
        for (int j = 1; j < 4; ++j) {
          float cc = (sj[j] + tr[j][kk]) + ev[kk];
          if (cc > best) { best = cc; bi = j; }
        }
        mw |= (unsigned)bi << (8 * kk);
      }
      mloc[k] = mw;
    } else {
      mloc[k] = ID;
    }
  }
  unsigned int P = mloc[15];
  #pragma unroll
  for (int k = 14; k >= 0; --k) P = compose_map(mloc[k], P);
  #pragma unroll
  for (int d = 1; d < 64; d <<= 1) {
    unsigned int q = (unsigned int)__shfl_down((int)P, d);
    if (lane + d > 63) q = ID;
    P = compose_map(P, q);
  }
  unsigned int E = (unsigned int)__shfl_down((int)P, 1);
  if (lane == 63) E = ID;
  const int last = s_last;
  unsigned int tag = (E >> (8 * last)) & 3u;
  int* ob = out + (size_t)b * Tn;
  #pragma unroll
  for (int k = 15; k >= 0; --k) {
    tag = (mloc[k] >> (8 * tag)) & 3u;
    ob[t0 + k] = (int)tag;
  }
}

extern "C" void kernel_launch(void* const* d_in, const int* in_sizes, int n_in,
                              void* d_out, int out_size, void* d_ws, size_t ws_size,
                              hipStream_t stream) {
  const float* x      = (const float*)d_in[0];
  const float* conv_w = (const float*)d_in[1];
  const float* conv_b = (const float*)d_in[2];
  const float* lin_w  = (const float*)d_in[3];
  const float* lin_b  = (const float*)d_in[4];
  const float* cstart = (const float*)d_in[5];
  const float* cend   = (const float*)d_in[6];
  const float* ctrans = (const float*)d_in[7];
  int* out = (int*)d_out;

  unsigned short* Bp = (unsigned short*)d_ws;              // 786,432 B
  float* em2 = (float*)((char*)d_ws + 786432);             // 2 MB partials

  pack_b_k<<<192, 256, 0, stream>>>(conv_w, Bp);
  emis_k<<<dim3(Tn / TT, 2, Bn), 256, 0, stream>>>(x, Bp, conv_b, lin_w, em2);
  viterbi_k<<<Bn, 64, 0, stream>>>(em2, lin_b, cstart, cend, ctrans, out);
}

// Round 12
// 134.015 us; speedup vs baseline: 2.6599x; 1.1077x over previous
//
#include <hip/hip_runtime.h>
#include <cstdint>
#include <cstddef>

typedef __attribute__((ext_vector_type(8))) short short8;
typedef __attribute__((ext_vector_type(4))) float f32x4;

constexpr int Bn = 64, Tn = 1024, Hn = 256, Kn = 4;
constexpr int TT = 128;           // T-rows per block
constexpr int AROWS = TT + 2;     // 130 staged x-rows (t0-1 .. t0+128)
constexpr int ARSTR = 144;        // A-LDS row stride bytes (128 data + 16 pad)

// round-to-nearest-even fp32 -> bf16 bits
__device__ __forceinline__ unsigned bf16rne(float f) {
  unsigned u = __float_as_uint(f);
  return (u + 0x7fffu + ((u >> 16) & 1u)) >> 16;
}

// Pack conv_w into MFMA-B-fragment-ready hi/lo bf16:
// Bp[fid(24 ks x 2 p x 16 nf)][lane(64)][j(8)], value = part_p(conv_w[n][i][dt])
// where k = ks*32 + (lane>>4)*8 + j (dt=k>>8, i=k&255), n = nf*16 + (lane&15).
__global__ __launch_bounds__(256) void pack_b_k(const float* __restrict__ conv_w,
                                                unsigned short* __restrict__ Bp) {
  int gt = blockIdx.x * 256 + threadIdx.x;   // 0..49151
  int fid = gt >> 6, l = gt & 63;
  int ks = fid >> 5, rem = fid & 31;
  int p = rem >> 4, nf = rem & 15;
  int n = nf * 16 + (l & 15);
  int k0 = ks * 32 + ((l >> 4) << 3);
  short8 s;
  #pragma unroll
  for (int j = 0; j < 8; ++j) {
    int k = k0 + j;
    int dt = k >> 8, i = k & 255;
    float w = conv_w[n * 768 + i * 3 + dt];
    unsigned hb = bf16rne(w);
    if (p == 0) s[j] = (short)hb;
    else        s[j] = (short)bf16rne(w - __uint_as_float(hb << 16));
  }
  *reinterpret_cast<short8*>(Bp + (size_t)fid * 512 + l * 8) = s;
}

// Fused conv1d(k=3,pad=1)+bias+ReLU+Linear(256->4) via bf16 3-way-split MFMA
// (AhBh + AlBh + AhBl; dropped AlBl term <= 2^-18 relative).
// Block: 128(T) x 128(N), 4 waves (64x64 each = 4x4 16x16 frags).
// A: hi/lo bf16 in LDS (ONLY LDS use, 18,720 B), staged per 32-chan group.
// B: fragment-packed, read DIRECTLY global->VGPR (L2-hot, shared by 512
// blocks), double-set rotation with static parity-unrolled assignment.
// Barriers only around the 8 A-restages; B loads fly across them.
__global__ __launch_bounds__(256, 3) void emis_k(const float* __restrict__ x,
    const unsigned short* __restrict__ Bp, const float* __restrict__ conv_b,
    const float* __restrict__ lin_w, float* __restrict__ em2) {
  __shared__ __align__(16) char A_lds[AROWS * ARSTR];   // 18,720 B

  const int b = blockIdx.z, ny = blockIdx.y, t0 = blockIdx.x * TT;
  const int tid = threadIdx.x, lane = tid & 63, w = tid >> 6;
  const int wm = w >> 1, wn = w & 1;
  const float* xb = x + (size_t)b * Tn * Hn;

  auto stageA = [&](int ig) {
    #pragma unroll 1
    for (int it = 0; it < 5; ++it) {
      int idx = it * 256 + tid;
      if (idx < AROWS * 8) {
        int row = idx >> 3, c4 = idx & 7;
        int trow = t0 - 1 + row;
        float4 v = make_float4(0.f, 0.f, 0.f, 0.f);
        if (trow >= 0 && trow < Tn)
          v = *reinterpret_cast<const float4*>(xb + (size_t)trow * Hn + ig * 32 + c4 * 4);
        unsigned h[4], lo[4];
        float vf[4] = {v.x, v.y, v.z, v.w};
        #pragma unroll
        for (int q = 0; q < 4; ++q) {
          h[q] = bf16rne(vf[q]);
          lo[q] = bf16rne(vf[q] - __uint_as_float(h[q] << 16));
        }
        uint2 hp, lp;
        hp.x = h[0] | (h[1] << 16);  hp.y = h[2] | (h[3] << 16);
        lp.x = lo[0] | (lo[1] << 16); lp.y = lo[2] | (lo[3] << 16);
        char* base = A_lds + row * ARSTR + c4 * 8;
        *reinterpret_cast<uint2*>(base) = hp;        // hi plane
        *reinterpret_cast<uint2*>(base + 64) = lp;   // lo plane
      }
    }
  };

  // B-fragment source base for this wave (its 4 nf x 2 p frags per step)
  const char* bsrc = reinterpret_cast<const char*>(Bp)
      + (size_t)(ny * 8 + wn * 4) * 1024 + lane * 16;
  auto loadB = [&](short8* Bh, short8* Bl, int ks) {
    #pragma unroll
    for (int nf = 0; nf < 4; ++nf) {
      Bh[nf] = *reinterpret_cast<const short8*>(bsrc + (size_t)((ks * 2 + 0) * 16 + nf) * 1024);
      Bl[nf] = *reinterpret_cast<const short8*>(bsrc + (size_t)((ks * 2 + 1) * 16 + nf) * 1024);
    }
  };

  f32x4 acc[4][4];
  #pragma unroll
  for (int mf = 0; mf < 4; ++mf)
    #pragma unroll
    for (int nf = 0; nf < 4; ++nf) acc[mf][nf] = (f32x4)0.f;

  // per-lane A base: row=(lane&15), k-chans=(lane>>4)*8 (16B), +wm 64-row block
  const char* aB = A_lds + (lane & 15) * ARSTR + ((lane >> 4) << 4) + wm * 64 * ARSTR;

// one K-step: consume (BH,BL), prefetch next ks into (NBH,NBL)
#define STEP(DT, BH, BL, NBH, NBL, KSN)                                       \
  {                                                                           \
    loadB(NBH, NBL, (KSN));                                                   \
    __builtin_amdgcn_s_setprio(1);                                            \
    _Pragma("unroll")                                                         \
    for (int mf = 0; mf < 4; ++mf) {                                          \
      const char* ap = aB + (mf * 16 + (DT)) * ARSTR;                         \
      short8 Ah = *reinterpret_cast<const short8*>(ap);                       \
      short8 Al = *reinterpret_cast<const short8*>(ap + 64);                  \
      _Pragma("unroll")                                                       \
      for (int nf = 0; nf < 4; ++nf) {                                        \
        f32x4 c = acc[mf][nf];                                                \
        c = __builtin_amdgcn_mfma_f32_16x16x32_bf16(Ah, BH[nf], c, 0, 0, 0);  \
        c = __builtin_amdgcn_mfma_f32_16x16x32_bf16(Al, BH[nf], c, 0, 0, 0);  \
        c = __builtin_amdgcn_mfma_f32_16x16x32_bf16(Ah, BL[nf], c, 0, 0, 0);  \
        acc[mf][nf] = c;                                                      \
      }                                                                       \
    }                                                                         \
    __builtin_amdgcn_s_setprio(0);                                            \
  }

  short8 BhA[4], BlA[4], BhB[4], BlB[4];
  loadB(BhA, BlA, 0);                 // (ig0, dt0)
  stageA(0);
  __syncthreads();

  #pragma unroll 1
  for (int igp = 0; igp < 4; ++igp) {
    const int ig0 = igp * 2, ig1 = ig0 + 1;
    // even ig: sets A,B,A
    STEP(0, BhA, BlA, BhB, BlB, 8 + ig0);
    STEP(1, BhB, BlB, BhA, BlA, 16 + ig0);
    STEP(2, BhA, BlA, BhB, BlB, ig1);
    __syncthreads();                  // all waves done reading A(ig0)
    stageA(ig1);
    __syncthreads();
    // odd ig: sets B,A,B
    STEP(0, BhB, BlB, BhA, BlA, 8 + ig1);
    STEP(1, BhA, BlA, BhB, BlB, 16 + ig1);
    STEP(2, BhB, BlB, BhA, BlA, (ig1 < 7 ? ig1 + 1 : 0));
    if (igp < 3) {
      __syncthreads();
      stageA(ig1 + 1);
      __syncthreads();
    }
  }
#undef STEP

  // ---- Epilogue: +conv_b, ReLU, x lin_w^T partials over this wave's cols ----
  // C/D layout: col = lane&15, row = (lane>>4)*4 + v  (m89-verified).
  f32x4 pem[4][4];   // [mf][v] -> 4 kk partial sums
  #pragma unroll
  for (int mf = 0; mf < 4; ++mf)
    #pragma unroll
    for (int v = 0; v < 4; ++v) pem[mf][v] = (f32x4)0.f;

  #pragma unroll
  for (int nf = 0; nf < 4; ++nf) {
    const int gcol = ny * 128 + wn * 64 + nf * 16 + (lane & 15);
    const float cb = conv_b[gcol];
    f32x4 lw;
    lw[0] = lin_w[gcol]; lw[1] = lin_w[256 + gcol];
    lw[2] = lin_w[512 + gcol]; lw[3] = lin_w[768 + gcol];
    #pragma unroll
    for (int mf = 0; mf < 4; ++mf)
      #pragma unroll
      for (int v = 0; v < 4; ++v) {
        float val = fmaxf(acc[mf][nf][v] + cb, 0.f);
        pem[mf][v] += val * lw;
      }
  }
  // reduce over the 16 col-lanes (lane bits 0..3)
  #pragma unroll
  for (int mf = 0; mf < 4; ++mf)
    #pragma unroll
    for (int v = 0; v < 4; ++v) {
      f32x4 t = pem[mf][v];
      #pragma unroll
      for (int m = 1; m < 16; m <<= 1) {
        f32x4 q;
        q[0] = __shfl_xor(t[0], m); q[1] = __shfl_xor(t[1], m);
        q[2] = __shfl_xor(t[2], m); q[3] = __shfl_xor(t[3], m);
        t += q;
      }
      pem[mf][v] = t;
    }
  __syncthreads();                    // all waves done with A_lds (reuse)
  // cross-wave (wn) combine via LDS
  float* red = reinterpret_cast<float*>(A_lds);   // [128 rows][2 wn][4 kk]
  if ((lane & 15) == 0) {
    const int g = lane >> 4;
    #pragma unroll
    for (int mf = 0; mf < 4; ++mf)
      #pragma unroll
      for (int v = 0; v < 4; ++v) {
        int r = wm * 64 + mf * 16 + g * 4 + v;
        *reinterpret_cast<f32x4*>(red + (r * 2 + wn) * 4) = pem[mf][v];
      }
  }
  __syncthreads();
  if (tid < 128) {
    f32x4 s0 = *reinterpret_cast<f32x4*>(red + tid * 8);
    f32x4 s1 = *reinterpret_cast<f32x4*>(red + tid * 8 + 4);
    f32x4 s = s0 + s1;
    *reinterpret_cast<f32x4*>(em2 + ((size_t)(b * Tn + t0 + tid) * 2 + ny) * 4) = s;
  }
}

// byte-map composition c(k) = a(b(k))
__device__ __forceinline__ unsigned int compose_map(unsigned int a, unsigned int b) {
#if __has_builtin(__builtin_amdgcn_perm)
  return __builtin_amdgcn_perm(a, a, b);
#else
  unsigned int c = 0;
  #pragma unroll
  for (int k = 0; k < 4; ++k) {
    unsigned int sel = (b >> (8 * k)) & 0xffu;
    c |= ((a >> (8 * sel)) & 0xffu) << (8 * k);
  }
  return c;
#endif
}

// quad_perm broadcast of lane J (within each 4-lane quad) via DPP
template <int J>
__device__ __forceinline__ float qb(float v) {
  return __int_as_float(__builtin_amdgcn_update_dpp(
      0, __float_as_int(v), (J * 0x55), 0xf, 0xf, true));
}

// One quad-parallel Viterbi step for lane k (values bitwise = scalar form).
#define PSTEP(EV, T)                                                       \
  {                                                                        \
    shf[((T) - 1) * 4 + kk] = s;                                           \
    float c0 = qb<0>(s) + trc0;                                            \
    float c1 = qb<1>(s) + trc1;                                            \
    float c2 = qb<2>(s) + trc2;                                            \
    float c3 = qb<3>(s) + trc3;                                            \
    s = fmaxf(fmaxf(c0, c1), fmaxf(c2, c3)) + (EV);                        \
  }

// CRF Viterbi decode. Stage: se[t] = em2[t][half0] + em2[t][half1] + lin_b.
// Forward: 4-lane quad-parallel scan. Backtrace: 64 lanes rebuild argmax
// maps, v_perm suffix-scan (integer-exact).
__global__ __launch_bounds__(64) void viterbi_k(const float* __restrict__ em2,
    const float* __restrict__ lin_b, const float* __restrict__ cstart,
    const float* __restrict__ cend, const float* __restrict__ ctrans,
    int* __restrict__ out) {
  __shared__ float4 se[Tn];          // emissions, 16 KB
  __shared__ float4 sh[Tn - 1];      // score vector BEFORE step t+1, 16 KB
  __shared__ int s_last;
  const int b = blockIdx.x, lane = threadIdx.x;
  const float4* e2 = reinterpret_cast<const float4*>(em2 + (size_t)b * Tn * 8);
  const float lb0 = lin_b[0], lb1 = lin_b[1], lb2 = lin_b[2], lb3 = lin_b[3];
  for (int i = lane; i < Tn; i += 64) {
    float4 a = e2[i * 2], c = e2[i * 2 + 1];
    se[i] = make_float4(a.x + c.x + lb0, a.y + c.y + lb1,
                        a.z + c.z + lb2, a.w + c.w + lb3);
  }
  float tr[4][4];
  #pragma unroll
  for (int j = 0; j < 4; ++j)
    #pragma unroll
    for (int k = 0; k < 4; ++k) tr[j][k] = ctrans[j * 4 + k];
  __syncthreads();

  if (lane < 4) {
    const int kk = lane;
    const float* sef = reinterpret_cast<const float*>(se);
    float* shf = reinterpret_cast<float*>(sh);
    const float trc0 = ctrans[0 * 4 + kk];
    const float trc1 = ctrans[1 * 4 + kk];
    const float trc2 = ctrans[2 * 4 + kk];
    const float trc3 = ctrans[3 * 4 + kk];
    float s = cstart[kk] + sef[kk];
    float e[8];
    #pragma unroll
    for (int d = 0; d < 8; ++d) e[d] = sef[(1 + d) * 4 + kk];
    int t = 1;
    #pragma unroll 1
    for (int g = 0; g < 127; ++g, t += 8) {   // t = 1..1016
      float f[8];
      #pragma unroll
      for (int d = 0; d < 8; ++d) f[d] = e[d];
      #pragma unroll
      for (int d = 0; d < 8; ++d) e[d] = sef[(t + 8 + d) * 4 + kk];
      PSTEP(f[0], t);     PSTEP(f[1], t + 1);
      PSTEP(f[2], t + 2); PSTEP(f[3], t + 3);
      PSTEP(f[4], t + 4); PSTEP(f[5], t + 5);
      PSTEP(f[6], t + 6); PSTEP(f[7], t + 7);
    }
    PSTEP(e[0], 1017); PSTEP(e[1], 1018); PSTEP(e[2], 1019);
    PSTEP(e[3], 1020); PSTEP(e[4], 1021); PSTEP(e[5], 1022);
    PSTEP(e[6], 1023);
    s += cend[kk];
    float f0 = __shfl(s, 0), f1 = __shfl(s, 1);
    float f2 = __shfl(s, 2), f3 = __shfl(s, 3);
    if (kk == 0) {
      int tag = 0; float bf = f0;
      if (f1 > bf) { bf = f1; tag = 1; }
      if (f2 > bf) { bf = f2; tag = 2; }
      if (f3 > bf) { bf = f3; tag = 3; }
      s_last = tag;
    }
  }
  __syncthreads();

  const unsigned int ID = 0x03020100u;
  unsigned int mloc[16];
  const int t0 = lane * 16;
  #pragma unroll
  for (int k = 0; k < 16; ++k) {
    const int t = t0 + k;
    if (t < Tn - 1) {
      const float4 s = sh[t];
      const float4 e = se[t + 1];
      const float sj[4] = {s.x, s.y, s.z, s.w};
      const float ev[4] = {e.x, e.y, e.z, e.w};
      unsigned int mw = 0;
      #pragma unroll
      for (int kk = 0; kk < 4; ++kk) {
        float best = (sj[0] + tr[0][kk]) + ev[kk];
        int bi = 0;
        #pragma unroll
        for (int j = 1; j < 4; ++j) {
          float cc = (sj[j] + tr[j][kk]) + ev[kk];
          if (cc > best) { best = cc; bi = j; }
        }
        mw |= (unsigned)bi << (8 * kk);
      }
      mloc[k] = mw;
    } else {
      mloc[k] = ID;
    }
  }
  unsigned int P = mloc[15];
  #pragma unroll
  for (int k = 14; k >= 0; --k) P = compose_map(mloc[k], P);
  #pragma unroll
  for (int d = 1; d < 64; d <<= 1) {
    unsigned int q = (unsigned int)__shfl_down((int)P, d);
    if (lane + d > 63) q = ID;
    P = compose_map(P, q);
  }
  unsigned int E = (unsigned int)__shfl_down((int)P, 1);
  if (lane == 63) E = ID;
  const int last = s_last;
  unsigned int tag = (E >> (8 * last)) & 3u;
  int* ob = out + (size_t)b * Tn;
  #pragma unroll
  for (int k = 15; k >= 0; --k) {
    tag = (mloc[k] >> (8 * tag)) & 3u;
    ob[t0 + k] = (int)tag;
  }
}

extern "C" void kernel_launch(void* const* d_in, const int* in_sizes, int n_in,
                              void* d_out, int out_size, void* d_ws, size_t ws_size,
                              hipStream_t stream) {
  const float* x      = (const float*)d_in[0];
  const float* conv_w = (const float*)d_in[1];
  const float* conv_b = (const float*)d_in[2];
  const float* lin_w  = (const float*)d_in[3];
  const float* lin_b  = (const float*)d_in[4];
  const float* cstart = (const float*)d_in[5];
  const float* cend   = (const float*)d_in[6];
  const float* ctrans = (const float*)d_in[7];
  int* out = (int*)d_out;

  unsigned short* Bp = (unsigned short*)d_ws;              // 786,432 B
  float* em2 = (float*)((char*)d_ws + 786432);             // 2 MB partials

  pack_b_k<<<192, 256, 0, stream>>>(conv_w, Bp);
  emis_k<<<dim3(Tn / TT, 2, Bn), 256, 0, stream>>>(x, Bp, conv_b, lin_w, em2);
  viterbi_k<<<Bn, 64, 0, stream>>>(em2, lin_b, cstart, cend, ctrans, out);
}

// Round 13
// 123.394 us; speedup vs baseline: 2.8889x; 1.0861x over previous
//
#include <hip/hip_runtime.h>
#include <cstdint>
#include <cstddef>

typedef __attribute__((ext_vector_type(8))) short short8;
typedef __attribute__((ext_vector_type(4))) float f32x4;

constexpr int Bn = 64, Tn = 1024, Hn = 256, Kn = 4;
constexpr int TT = 128;           // T-rows per block
constexpr int AROWS = TT + 2;     // 130 staged x-rows (t0-1 .. t0+128)
constexpr int ARSTR = 144;        // A-LDS row stride bytes (hi 64B + lo 64B + 16 pad)
constexpr int ABUFSZ = AROWS * ARSTR;   // 18,720 B per buffer

// round-to-nearest-even fp32 -> bf16 bits
__device__ __forceinline__ unsigned bf16rne(float f) {
  unsigned u = __float_as_uint(f);
  return (u + 0x7fffu + ((u >> 16) & 1u)) >> 16;
}

// Pack conv_w into MFMA-B-fragment-ready hi/lo bf16:
// Bp[fid(24 ks x 2 p x 16 nf)][lane(64)][j(8)], value = part_p(conv_w[n][i][dt])
// where k = ks*32 + (lane>>4)*8 + j (dt=k>>8, i=k&255), n = nf*16 + (lane&15).
__global__ __launch_bounds__(256) void pack_b_k(const float* __restrict__ conv_w,
                                                unsigned short* __restrict__ Bp) {
  int gt = blockIdx.x * 256 + threadIdx.x;   // 0..49151
  int fid = gt >> 6, l = gt & 63;
  int ks = fid >> 5, rem = fid & 31;
  int p = rem >> 4, nf = rem & 15;
  int n = nf * 16 + (l & 15);
  int k0 = ks * 32 + ((l >> 4) << 3);
  short8 s;
  #pragma unroll
  for (int j = 0; j < 8; ++j) {
    int k = k0 + j;
    int dt = k >> 8, i = k & 255;
    float w = conv_w[n * 768 + i * 3 + dt];
    unsigned hb = bf16rne(w);
    if (p == 0) s[j] = (short)hb;
    else        s[j] = (short)bf16rne(w - __uint_as_float(hb << 16));
  }
  *reinterpret_cast<short8*>(Bp + (size_t)fid * 512 + l * 8) = s;
}

// lgkm-only barrier: ds_writes visible, global VGPR loads keep flying
// (avoids __syncthreads()'s vmcnt(0) drain). Uniform control flow only.
#define GBAR() asm volatile("s_waitcnt lgkmcnt(0)\n\ts_barrier" ::: "memory")

// Fused conv1d(k=3,pad=1)+bias+ReLU+Linear(256->4) via bf16 3-way-split MFMA
// (AhBh + AlBh + AhBl; dropped AlBl <= 2^-18 relative).
// Block: 128(T) x 128(N), 4 waves (64x64 each = 4x4 16x16 frags).
// A: hi/lo bf16, DOUBLE-buffered LDS (2 x 18,720 B), 8 groups of 32 chans;
//    group g+1 global loads issued BEFORE group g's MFMAs (T14), ds_write
//    after, ONE lgkm-barrier per group.
// B: fragment-packed, global->VGPR double-set rotation (L2-hot), loads
//    cross barriers freely.
__global__ __launch_bounds__(256, 2) void emis_k(const float* __restrict__ x,
    const unsigned short* __restrict__ Bp, const float* __restrict__ conv_b,
    const float* __restrict__ lin_w, float* __restrict__ em2) {
  __shared__ __align__(16) char A_lds[2 * ABUFSZ];   // 37,440 B

  const int b = blockIdx.z, ny = blockIdx.y, t0 = blockIdx.x * TT;
  const int tid = threadIdx.x, lane = tid & 63, w = tid >> 6;
  const int wm = w >> 1, wn = w & 1;
  const float* xb = x + (size_t)b * Tn * Hn;

  float4 pre[5];                    // A-prefetch regs (20 VGPR)

  // issue group ig's global loads (no LDS touch)
  auto loadA = [&](int ig) {
    #pragma unroll
    for (int it = 0; it < 5; ++it) {
      int idx = it * 256 + tid;
      if (idx < AROWS * 8) {
        int row = idx >> 3, c4 = idx & 7;
        int trow = t0 - 1 + row;
        float4 v = make_float4(0.f, 0.f, 0.f, 0.f);
        if (trow >= 0 && trow < Tn)
          v = *reinterpret_cast<const float4*>(xb + (size_t)trow * Hn + ig * 32 + c4 * 4);
        pre[it] = v;
      }
    }
  };
  // convert + write pre[] into buffer at byte offset BOFF
  auto writeA = [&](int boff) {
    #pragma unroll
    for (int it = 0; it < 5; ++it) {
      int idx = it * 256 + tid;
      if (idx < AROWS * 8) {
        int row = idx >> 3, c4 = idx & 7;
        float vf[4] = {pre[it].x, pre[it].y, pre[it].z, pre[it].w};
        unsigned h[4], lo[4];
        #pragma unroll
        for (int q = 0; q < 4; ++q) {
          h[q] = bf16rne(vf[q]);
          lo[q] = bf16rne(vf[q] - __uint_as_float(h[q] << 16));
        }
        uint2 hp, lp;
        hp.x = h[0] | (h[1] << 16);  hp.y = h[2] | (h[3] << 16);
        lp.x = lo[0] | (lo[1] << 16); lp.y = lo[2] | (lo[3] << 16);
        char* base = A_lds + boff + row * ARSTR + c4 * 8;
        *reinterpret_cast<uint2*>(base) = hp;        // hi plane
        *reinterpret_cast<uint2*>(base + 64) = lp;   // lo plane
      }
    }
  };

  // B-fragment source base for this wave (4 nf x 2 p frags per step)
  const char* bsrc = reinterpret_cast<const char*>(Bp)
      + (size_t)(ny * 8 + wn * 4) * 1024 + lane * 16;
  auto loadB = [&](short8* Bh, short8* Bl, int ks) {
    #pragma unroll
    for (int nf = 0; nf < 4; ++nf) {
      Bh[nf] = *reinterpret_cast<const short8*>(bsrc + (size_t)((ks * 2 + 0) * 16 + nf) * 1024);
      Bl[nf] = *reinterpret_cast<const short8*>(bsrc + (size_t)((ks * 2 + 1) * 16 + nf) * 1024);
    }
  };

  f32x4 acc[4][4];
  #pragma unroll
  for (int mf = 0; mf < 4; ++mf)
    #pragma unroll
    for (int nf = 0; nf < 4; ++nf) acc[mf][nf] = (f32x4)0.f;

  // per-lane A base: row=(lane&15), k-chans=(lane>>4)*8 (16B), +wm 64-row block
  const char* aB = A_lds + (lane & 15) * ARSTR + ((lane >> 4) << 4) + wm * 64 * ARSTR;

// one K-step in buffer ABUF: consume (BH,BL), prefetch next ks into (NBH,NBL)
#define STEP(ABUF, DT, BH, BL, NBH, NBL, KSN)                                 \
  {                                                                           \
    loadB(NBH, NBL, (KSN));                                                   \
    __builtin_amdgcn_s_setprio(1);                                            \
    _Pragma("unroll")                                                         \
    for (int mf = 0; mf < 4; ++mf) {                                          \
      const char* ap = aB + (ABUF) + (mf * 16 + (DT)) * ARSTR;                \
      short8 Ah = *reinterpret_cast<const short8*>(ap);                       \
      short8 Al = *reinterpret_cast<const short8*>(ap + 64);                  \
      _Pragma("unroll")                                                       \
      for (int nf = 0; nf < 4; ++nf) {                                        \
        f32x4 c = acc[mf][nf];                                                \
        c = __builtin_amdgcn_mfma_f32_16x16x32_bf16(Ah, BH[nf], c, 0, 0, 0);  \
        c = __builtin_amdgcn_mfma_f32_16x16x32_bf16(Al, BH[nf], c, 0, 0, 0);  \
        c = __builtin_amdgcn_mfma_f32_16x16x32_bf16(Ah, BL[nf], c, 0, 0, 0);  \
        acc[mf][nf] = c;                                                      \
      }                                                                       \
    }                                                                         \
    __builtin_amdgcn_s_setprio(0);                                            \
  }

  short8 BhA[4], BlA[4], BhB[4], BlB[4];
  // prologue: A group 0 -> buf0 (latency exposed once), B ks=0 in flight
  loadA(0);
  loadB(BhA, BlA, 0);
  writeA(0);
  GBAR();

  #pragma unroll 1
  for (int igp = 0; igp < 4; ++igp) {
    const int ig0 = igp * 2, ig1 = ig0 + 1;
    // ---- group ig0 in buf0 (consumes sets A,B,A) ----
    loadA(ig1);                                  // issue-early for buf1
    STEP(0, 0, BhA, BlA, BhB, BlB, 8 + ig0);
    STEP(0, 1, BhB, BlB, BhA, BlA, 16 + ig0);
    STEP(0, 2, BhA, BlA, BhB, BlB, ig1);
    writeA(ABUFSZ);                              // write-late into buf1
    GBAR();
    // ---- group ig1 in buf1 (consumes sets B,A,B) ----
    if (ig1 < 7) loadA(ig1 + 1);
    STEP(ABUFSZ, 0, BhB, BlB, BhA, BlA, 8 + ig1);
    STEP(ABUFSZ, 1, BhA, BlA, BhB, BlB, 16 + ig1);
    STEP(ABUFSZ, 2, BhB, BlB, BhA, BlA, (ig1 < 7 ? ig1 + 1 : 0));
    if (ig1 < 7) writeA(0);
    GBAR();
  }
#undef STEP

  // ---- Epilogue: +conv_b, ReLU, x lin_w^T partials over this wave's cols ----
  // C/D layout: col = lane&15, row = (lane>>4)*4 + v  (m89-verified).
  f32x4 pem[4][4];   // [mf][v] -> 4 kk partial sums
  #pragma unroll
  for (int mf = 0; mf < 4; ++mf)
    #pragma unroll
    for (int v = 0; v < 4; ++v) pem[mf][v] = (f32x4)0.f;

  #pragma unroll
  for (int nf = 0; nf < 4; ++nf) {
    const int gcol = ny * 128 + wn * 64 + nf * 16 + (lane & 15);
    const float cb = conv_b[gcol];
    f32x4 lw;
    lw[0] = lin_w[gcol]; lw[1] = lin_w[256 + gcol];
    lw[2] = lin_w[512 + gcol]; lw[3] = lin_w[768 + gcol];
    #pragma unroll
    for (int mf = 0; mf < 4; ++mf)
      #pragma unroll
      for (int v = 0; v < 4; ++v) {
        float val = fmaxf(acc[mf][nf][v] + cb, 0.f);
        pem[mf][v] += val * lw;
      }
  }
  // reduce over the 16 col-lanes (lane bits 0..3)
  #pragma unroll
  for (int mf = 0; mf < 4; ++mf)
    #pragma unroll
    for (int v = 0; v < 4; ++v) {
      f32x4 t = pem[mf][v];
      #pragma unroll
      for (int m = 1; m < 16; m <<= 1) {
        f32x4 q;
        q[0] = __shfl_xor(t[0], m); q[1] = __shfl_xor(t[1], m);
        q[2] = __shfl_xor(t[2], m); q[3] = __shfl_xor(t[3], m);
        t += q;
      }
      pem[mf][v] = t;
    }
  __syncthreads();                    // all waves done with A_lds (reuse)
  // cross-wave (wn) combine via LDS
  float* red = reinterpret_cast<float*>(A_lds);   // [128 rows][2 wn][4 kk]
  if ((lane & 15) == 0) {
    const int g = lane >> 4;
    #pragma unroll
    for (int mf = 0; mf < 4; ++mf)
      #pragma unroll
      for (int v = 0; v < 4; ++v) {
        int r = wm * 64 + mf * 16 + g * 4 + v;
        *reinterpret_cast<f32x4*>(red + (r * 2 + wn) * 4) = pem[mf][v];
      }
  }
  __syncthreads();
  if (tid < 128) {
    f32x4 s0 = *reinterpret_cast<f32x4*>(red + tid * 8);
    f32x4 s1 = *reinterpret_cast<f32x4*>(red + tid * 8 + 4);
    f32x4 s = s0 + s1;
    *reinterpret_cast<f32x4*>(em2 + ((size_t)(b * Tn + t0 + tid) * 2 + ny) * 4) = s;
  }
}

// byte-map composition c(k) = a(b(k))
__device__ __forceinline__ unsigned int compose_map(unsigned int a, unsigned int b) {
#if __has_builtin(__builtin_amdgcn_perm)
  return __builtin_amdgcn_perm(a, a, b);
#else
  unsigned int c = 0;
  #pragma unroll
  for (int k = 0; k < 4; ++k) {
    unsigned int sel = (b >> (8 * k)) & 0xffu;
    c |= ((a >> (8 * sel)) & 0xffu) << (8 * k);
  }
  return c;
#endif
}

// quad_perm broadcast of lane J (within each 4-lane quad) via DPP
template <int J>
__device__ __forceinline__ float qb(float v) {
  return __int_as_float(__builtin_amdgcn_update_dpp(
      0, __float_as_int(v), (J * 0x55), 0xf, 0xf, true));
}

// One quad-parallel Viterbi step for lane k (values bitwise = scalar form).
#define PSTEP(EV, T)                                                       \
  {                                                                        \
    shf[((T) - 1) * 4 + kk] = s;                                           \
    float c0 = qb<0>(s) + trc0;                                            \
    float c1 = qb<1>(s) + trc1;                                            \
    float c2 = qb<2>(s) + trc2;                                            \
    float c3 = qb<3>(s) + trc3;                                            \
    s = fmaxf(fmaxf(c0, c1), fmaxf(c2, c3)) + (EV);                        \
  }

// CRF Viterbi decode. Stage: se[t] = em2[t][half0] + em2[t][half1] + lin_b.
// Forward: 4-lane quad-parallel scan. Backtrace: 64 lanes rebuild argmax
// maps, v_perm suffix-scan (integer-exact).
__global__ __launch_bounds__(64) void viterbi_k(const float* __restrict__ em2,
    const float* __restrict__ lin_b, const float* __restrict__ cstart,
    const float* __restrict__ cend, const float* __restrict__ ctrans,
    int* __restrict__ out) {
  __shared__ float4 se[Tn];          // emissions, 16 KB
  __shared__ float4 sh[Tn - 1];      // score vector BEFORE step t+1, 16 KB
  __shared__ int s_last;
  const int b = blockIdx.x, lane = threadIdx.x;
  const float4* e2 = reinterpret_cast<const float4*>(em2 + (size_t)b * Tn * 8);
  const float lb0 = lin_b[0], lb1 = lin_b[1], lb2 = lin_b[2], lb3 = lin_b[3];
  for (int i = lane; i < Tn; i += 64) {
    float4 a = e2[i * 2], c = e2[i * 2 + 1];
    se[i] = make_float4(a.x + c.x + lb0, a.y + c.y + lb1,
                        a.z + c.z + lb2, a.w + c.w + lb3);
  }
  float tr[4][4];
  #pragma unroll
  for (int j = 0; j < 4; ++j)
    #pragma unroll
    for (int k = 0; k < 4; ++k) tr[j][k] = ctrans[j * 4 + k];
  __syncthreads();

  if (lane < 4) {
    const int kk = lane;
    const float* sef = reinterpret_cast<const float*>(se);
    float* shf = reinterpret_cast<float*>(sh);
    const float trc0 = ctrans[0 * 4 + kk];
    const float trc1 = ctrans[1 * 4 + kk];
    const float trc2 = ctrans[2 * 4 + kk];
    const float trc3 = ctrans[3 * 4 + kk];
    float s = cstart[kk] + sef[kk];
    float e[8];
    #pragma unroll
    for (int d = 0; d < 8; ++d) e[d] = sef[(1 + d) * 4 + kk];
    int t = 1;
    #pragma unroll 1
    for (int g = 0; g < 127; ++g, t += 8) {   // t = 1..1016
      float f[8];
      #pragma unroll
      for (int d = 0; d < 8; ++d) f[d] = e[d];
      #pragma unroll
      for (int d = 0; d < 8; ++d) e[d] = sef[(t + 8 + d) * 4 + kk];
      PSTEP(f[0], t);     PSTEP(f[1], t + 1);
      PSTEP(f[2], t + 2); PSTEP(f[3], t + 3);
      PSTEP(f[4], t + 4); PSTEP(f[5], t + 5);
      PSTEP(f[6], t + 6); PSTEP(f[7], t + 7);
    }
    PSTEP(e[0], 1017); PSTEP(e[1], 1018); PSTEP(e[2], 1019);
    PSTEP(e[3], 1020); PSTEP(e[4], 1021); PSTEP(e[5], 1022);
    PSTEP(e[6], 1023);
    s += cend[kk];
    float f0 = __shfl(s, 0), f1 = __shfl(s, 1);
    float f2 = __shfl(s, 2), f3 = __shfl(s, 3);
    if (kk == 0) {
      int tag = 0; float bf = f0;
      if (f1 > bf) { bf = f1; tag = 1; }
      if (f2 > bf) { bf = f2; tag = 2; }
      if (f3 > bf) { bf = f3; tag = 3; }
      s_last = tag;
    }
  }
  __syncthreads();

  const unsigned int ID = 0x03020100u;
  unsigned int mloc[16];
  const int t0 = lane * 16;
  #pragma unroll
  for (int k = 0; k < 16; ++k) {
    const int t = t0 + k;
    if (t < Tn - 1) {
      const float4 s = sh[t];
      const float4 e = se[t + 1];
      const float sj[4] = {s.x, s.y, s.z, s.w};
      const float ev[4] = {e.x, e.y, e.z, e.w};
      unsigned int mw = 0;
      #pragma unroll
      for (int kk = 0; kk < 4; ++kk) {
        float best = (sj[0] + tr[0][kk]) + ev[kk];
        int bi = 0;
        #pragma unroll
        for (int j = 1; j < 4; ++j) {
          float cc = (sj[j] + tr[j][kk]) + ev[kk];
          if (cc > best) { best = cc; bi = j; }
        }
        mw |= (unsigned)bi << (8 * kk);
      }
      mloc[k] = mw;
    } else {
      mloc[k] = ID;
    }
  }
  unsigned int P = mloc[15];
  #pragma unroll
  for (int k = 14; k >= 0; --k) P = compose_map(mloc[k], P);
  #pragma unroll
  for (int d = 1; d < 64; d <<= 1) {
    unsigned int q = (unsigned int)__shfl_down((int)P, d);
    if (lane + d > 63) q = ID;
    P = compose_map(P, q);
  }
  unsigned int E = (unsigned int)__shfl_down((int)P, 1);
  if (lane == 63) E = ID;
  const int last = s_last;
  unsigned int tag = (E >> (8 * last)) & 3u;
  int* ob = out + (size_t)b * Tn;
  #pragma unroll
  for (int k = 15; k >= 0; --k) {
    tag = (mloc[k] >> (8 * tag)) & 3u;
    ob[t0 + k] = (int)tag;
  }
}

extern "C" void kernel_launch(void* const* d_in, const int* in_sizes, int n_in,
                              void* d_out, int out_size, void* d_ws, size_t ws_size,
                              hipStream_t stream) {
  const float* x      = (const float*)d_in[0];
  const float* conv_w = (const float*)d_in[1];
  const float* conv_b = (const float*)d_in[2];
  const float* lin_w  = (const float*)d_in[3];
  const float* lin_b  = (const float*)d_in[4];
  const float* cstart = (const float*)d_in[5];
  const float* cend   = (const float*)d_in[6];
  const float* ctrans = (const float*)d_in[7];
  int* out = (int*)d_out;

  unsigned short* Bp = (unsigned short*)d_ws;              // 786,432 B
  float* em2 = (float*)((char*)d_ws + 786432);             // 2 MB partials

  pack_b_k<<<192, 256, 0, stream>>>(conv_w, Bp);
  emis_k<<<dim3(Tn / TT, 2, Bn), 256, 0, stream>>>(x, Bp, conv_b, lin_w, em2);
  viterbi_k<<<Bn, 64, 0, stream>>>(em2, lin_b, cstart, cend, ctrans, out);
}